// Round 6
// baseline (466.680 us; speedup 1.0000x reference)
//
#include <hip/hip_runtime.h>
#include <hip/hip_fp16.h>

// ---------------------------------------------------------------------------
// Heads: per-head QKV projections + causal attention, B=4 T=1024 C=1024 H=8.
// Round 6: round-5 base + counted intra-phase lgkmcnt: MFMA cluster split into
// 4 groups gated by lgkmcnt(3/2/1/0) so ds_read latency of later A-fragments
// hides under earlier MFMA groups (the m201 template's counted-lgkm idiom).
// Read issue order pinned with sched_barrier(0) so counts gate the right regs.
// ---------------------------------------------------------------------------

typedef unsigned short u16;
typedef _Float16 f16x8 __attribute__((ext_vector_type(8)));
typedef float f32x4 __attribute__((ext_vector_type(4)));

__device__ __forceinline__ u16 f2h(float f) {
    union { __half h; u16 u; } cv;
    cv.h = __float2half(f);
    return cv.u;
}

// global -> LDS direct copy, 16B/lane (wave-uniform LDS base + lane*16).
__device__ __forceinline__ void gload_lds16(const u16* g, const u16* lds_base, unsigned off_bytes) {
    unsigned a32 = (unsigned)(uintptr_t)((const char*)lds_base + off_bytes);
    a32 = __builtin_amdgcn_readfirstlane(a32);
    __builtin_amdgcn_global_load_lds(
        (const __attribute__((address_space(1))) void*)(uintptr_t)g,
        (__attribute__((address_space(3))) void*)a32,
        16, 0, 0);
}

// ---------------------------------------------------------------------------
// gemm256: D[m,n] = scale * sum_k A[m,k] * Bt[n,k]  (both operands [rows][K])
// 256x256 tile, BK=64, 512 threads = 8 waves (2M x 4N), per-wave 128x64 out.
// LDS: [dbuf 2][mat 2][khalf 2] x (256 rows x 32 cols fp16 = 16KB) = 128 KB.
// Swizzle (T2): byte ^= ((row>>1)&3)<<4  (2-way residual, free).
// OM: 0 = fp16 out, 2 = fp32 out + causal tile skip, 3 = fp32 + causal K-limit.
// z-batch: offsets (z>>3)*hi + (z&7)*lo.
// ---------------------------------------------------------------------------
template <int OM>
__global__ __launch_bounds__(512, 2) void gemm256(
    const u16* __restrict__ A, const u16* __restrict__ Bt, void* __restrict__ Cout,
    int lda, int ldb, int ldc,
    long sA_hi, long sA_lo, long sB_hi, long sB_lo, long sC_hi, long sC_lo,
    int K, float scale)
{
    const int tile_n = blockIdx.x, z = blockIdx.z;
    // PV balance: pair long-K with short-K blocks across the two z-halves.
    const int tile_m = (OM == 3 && (z & 16)) ? (gridDim.y - 1 - blockIdx.y)
                                             : blockIdx.y;
    if (OM == 2 && tile_n > tile_m) return;  // causal: skip upper-tri tiles

    const int zh = z >> 3, zl = z & 7;
    const u16* Ab = A + (size_t)zh * sA_hi + (size_t)zl * sA_lo + (size_t)tile_m * 256 * lda;
    const u16* Bb = Bt + (size_t)zh * sB_hi + (size_t)zl * sB_lo + (size_t)tile_n * 256 * ldb;

    __shared__ u16 lds[8 * 8192];  // halfbase(db,mat,ks) = ((db<<2)|(mat<<1)|ks)*8192

    const int t = threadIdx.x, w = t >> 6, l = t & 63;
    const int wm = w >> 2, wn = w & 3;
    const int frow = l & 15, fch = l >> 4;

    const int Kend = (OM == 3) ? min(K, (tile_m + 1) * 256) : K;
    const int NT = Kend / 64;  // even, >= 4 at all call sites

    // staging constants: linear chunk clin -> logical (row, chunk) involution
    const int clin = w * 64 + l;
    const int srow = clin >> 2;
    const int sch = (clin & 3) ^ ((clin >> 3) & 3);
    const long eA = (long)srow * lda + sch * 8;
    const long eB = (long)srow * ldb + sch * 8;

    f32x4 acc[8][4] = {};
    f16x8 af[4], bf[4];

    // STAGE one K-half (16KB): mat 0=A 1=B, ks 0/1, tile tt, dbuf db
#define STAGE(DB, MAT, KS, TT) do {                                            \
        const u16* g_ = (MAT == 0 ? Ab + (size_t)(TT) * 64 + (KS) * 32 + eA    \
                                  : Bb + (size_t)(TT) * 64 + (KS) * 32 + eB);  \
        const u16* hb_ = lds + ((((DB) << 2) | ((MAT) << 1) | (KS)) << 13);    \
        gload_lds16(g_, hb_, (unsigned)(w * 64 * 16));                         \
        gload_lds16(g_ + (size_t)128 * (MAT == 0 ? lda : ldb), hb_,            \
                    (unsigned)((512 + w * 64) * 16));                          \
    } while (0)

    // swizzled fragment read
#define RD(DB, MAT, KS, ROW)                                                   \
    (*(const f16x8*)((const char*)(lds + ((((DB) << 2) | ((MAT) << 1) | (KS)) << 13)) + \
                     ((unsigned)((ROW) * 64 + fch * 16) ^ ((((ROW) >> 1) & 3) << 4))))

#define VM6 do { asm volatile("s_waitcnt vmcnt(6)"); \
                 __builtin_amdgcn_sched_barrier(0); } while (0)
#define VM0 do { asm volatile("s_waitcnt vmcnt(0)"); \
                 __builtin_amdgcn_sched_barrier(0); } while (0)
#define NOPW ((void)0)

    // one MFMA group: wait until af[M4] (and bf, issued earlier) are resident
#define MG(M4, CNT) do {                                                       \
        asm volatile("s_waitcnt lgkmcnt(" #CNT ")");                           \
        __builtin_amdgcn_sched_barrier(0);                                     \
        _Pragma("unroll") for (int ni = 0; ni < 4; ++ni)                       \
            acc[MHC * 4 + (M4)][ni] = __builtin_amdgcn_mfma_f32_16x16x32_f16(  \
                af[M4], bf[ni], acc[MHC * 4 + (M4)][ni], 0, 0, 0);             \
    } while (0)

    // one phase: pinned ds-reads | prefetch | bar | 4x{lgkm-gated MFMA} | wait | bar
#define PH(DB, KS, MH, WAITC, ...) do {                                        \
        const int MHC = (MH);                                                  \
        if ((MH) == 0) {                                                       \
            _Pragma("unroll") for (int ni = 0; ni < 4; ++ni)                   \
                bf[ni] = RD(DB, 1, KS, wn * 64 + ni * 16 + frow);              \
        }                                                                      \
        af[0] = RD(DB, 0, KS, wm * 128 + ((MH) * 4 + 0) * 16 + frow);          \
        __builtin_amdgcn_sched_barrier(0);                                     \
        af[1] = RD(DB, 0, KS, wm * 128 + ((MH) * 4 + 1) * 16 + frow);          \
        __builtin_amdgcn_sched_barrier(0);                                     \
        af[2] = RD(DB, 0, KS, wm * 128 + ((MH) * 4 + 2) * 16 + frow);          \
        __builtin_amdgcn_sched_barrier(0);                                     \
        af[3] = RD(DB, 0, KS, wm * 128 + ((MH) * 4 + 3) * 16 + frow);          \
        __builtin_amdgcn_sched_barrier(0);                                     \
        __VA_ARGS__;                                                           \
        __builtin_amdgcn_sched_barrier(0);                                     \
        __builtin_amdgcn_s_barrier();                                          \
        __builtin_amdgcn_s_setprio(1);                                         \
        MG(0, 3); MG(1, 2); MG(2, 1); MG(3, 0);                                \
        __builtin_amdgcn_s_setprio(0);                                         \
        __builtin_amdgcn_sched_barrier(0);                                     \
        WAITC;                                                                 \
        __builtin_amdgcn_s_barrier();                                          \
    } while (0)

    // prologue: tile0 (4 halves) + tile1 (3 halves; A-ks1(1) issued at p0)
    STAGE(0, 1, 0, 0); STAGE(0, 0, 0, 0); STAGE(0, 1, 1, 0); STAGE(0, 0, 1, 0);
    STAGE(1, 1, 0, 1); STAGE(1, 0, 0, 1); STAGE(1, 1, 1, 1);
    VM6;  // tile0's 4 halves landed (last 3 halves = 6 loads outstanding)
    __builtin_amdgcn_s_barrier();

    for (int tt = 0; tt < NT; tt += 2) {
        const bool more = (tt + 2) < NT;  // NT even => tt+3 < NT iff tt+2 < NT
        PH(0, 0, 0, NOPW, STAGE(1, 0, 1, tt + 1));              // p0
        PH(0, 0, 1, NOPW, if (more) STAGE(0, 1, 0, tt + 2));    // p1
        PH(0, 1, 0, NOPW, if (more) STAGE(0, 0, 0, tt + 2));    // p2
        PH(0, 1, 1, if (more) VM6; else VM0,
                    if (more) STAGE(0, 1, 1, tt + 2));          // p3: tile t+1 ready
        PH(1, 0, 0, NOPW, if (more) STAGE(0, 0, 1, tt + 2));    // p4
        PH(1, 0, 1, NOPW, if (more) STAGE(1, 1, 0, tt + 3));    // p5
        PH(1, 1, 0, NOPW, if (more) STAGE(1, 0, 0, tt + 3));    // p6
        PH(1, 1, 1, if (more) VM6; else VM0,
                    if (more) STAGE(1, 1, 1, tt + 3));          // p7: tile t+2 ready
    }
#undef PH
#undef MG
#undef RD
#undef STAGE

    // epilogue: C/D layout col = l&15, row = (l>>4)*4 + r
    const int r0 = (l >> 4) * 4, cc = l & 15;
    const size_t cb_off = (size_t)zh * sC_hi + (size_t)zl * sC_lo;
#pragma unroll
    for (int mi = 0; mi < 8; ++mi) {
#pragma unroll
        for (int r = 0; r < 4; ++r) {
            size_t grow = (size_t)(tile_m * 256 + wm * 128 + mi * 16 + r0 + r);
#pragma unroll
            for (int ni = 0; ni < 4; ++ni) {
                int gcol = tile_n * 256 + wn * 64 + ni * 16 + cc;
                float v = acc[mi][ni][r] * scale;
                if (OM == 0)
                    ((u16*)Cout)[cb_off + grow * ldc + gcol] = f2h(v);
                else
                    ((float*)Cout)[cb_off + grow * ldc + gcol] = v;
            }
        }
    }
}

// ---------------------------------------------------------------------------
// single-pass causal softmax, T=1024: S fp32 [Z,T,T] -> P fp16 [Z,T,T]
// row in registers (4 floats/thread); zero-fill to round256(t+1) for PV.
// ---------------------------------------------------------------------------
__global__ __launch_bounds__(256) void softmax_causal(
    const float* __restrict__ S, u16* __restrict__ P)
{
    const int T = 1024;
    const int tq = blockIdx.x, z = blockIdx.y;
    const float* row = S + ((size_t)z * T + tq) * T;
    u16* prow = P + ((size_t)z * T + tq) * T;
    const int n = tq + 1;
    const int nw = ((tq >> 8) + 1) << 8;  // 256-rounded write limit
    const int tid = threadIdx.x;
    const int i0 = tid * 4;

    float4 v = ((const float4*)row)[tid];
    float e0 = (i0 + 0 < n) ? v.x : -1e30f;
    float e1 = (i0 + 1 < n) ? v.y : -1e30f;
    float e2 = (i0 + 2 < n) ? v.z : -1e30f;
    float e3 = (i0 + 3 < n) ? v.w : -1e30f;

    float m = fmaxf(fmaxf(e0, e1), fmaxf(e2, e3));
#pragma unroll
    for (int o = 1; o < 64; o <<= 1) m = fmaxf(m, __shfl_xor(m, o));
    __shared__ float red[4];
    if ((tid & 63) == 0) red[tid >> 6] = m;
    __syncthreads();
    m = fmaxf(fmaxf(red[0], red[1]), fmaxf(red[2], red[3]));

    float p0 = __expf(e0 - m), p1 = __expf(e1 - m);
    float p2 = __expf(e2 - m), p3 = __expf(e3 - m);
    float s = p0 + p1 + p2 + p3;
#pragma unroll
    for (int o = 1; o < 64; o <<= 1) s += __shfl_xor(s, o);
    __shared__ float red2[4];
    if ((tid & 63) == 0) red2[tid >> 6] = s;
    __syncthreads();
    const float inv = 1.0f / (red2[0] + red2[1] + red2[2] + red2[3]);

    if (i0 < nw) {
        ushort4 o4;
        o4.x = f2h(p0 * inv); o4.y = f2h(p1 * inv);
        o4.z = f2h(p2 * inv); o4.w = f2h(p3 * inv);
        ((ushort4*)prow)[tid] = o4;
    }
}

__global__ void cast_f32_f16(const float* __restrict__ src, u16* __restrict__ dst, int n4)
{
    int i = blockIdx.x * 256 + threadIdx.x;
    if (i < n4) {
        float4 v = ((const float4*)src)[i];
        ushort4 o;
        o.x = f2h(v.x); o.y = f2h(v.y); o.z = f2h(v.z); o.w = f2h(v.w);
        ((ushort4*)dst)[i] = o;
    }
}

extern "C" void kernel_launch(void* const* d_in, const int* in_sizes, int n_in,
                              void* d_out, int out_size, void* d_ws, size_t ws_size,
                              hipStream_t stream)
{
    (void)in_sizes; (void)n_in; (void)out_size; (void)ws_size;
    const int B = 4, T = 1024, C = 1024, H = 8;
    const int BT = B * T;   // 4096
    const int HC = H * C;   // 8192

    const float* data = (const float*)d_in[0];
    const float* Wq = (const float*)d_in[1];
    const float* Wk = (const float*)d_in[2];
    const float* Wv = (const float*)d_in[3];
    float* out = (float*)d_out;

    // workspace (440 MiB of the 512 MiB ws)
    char* p = (char*)d_ws;
    const size_t nData = (size_t)BT * C;      // 4M
    const size_t nW = (size_t)H * C * C;      // 8M
    const size_t nAll = (size_t)BT * HC;      // 32M
    const size_t nS = (size_t)B * H * T * T;  // 32M
    u16* dataH = (u16*)p; p += nData * 2;     //   8 MiB
    u16* WqH = (u16*)p; p += nW * 2;          //  16 MiB
    u16* WkH = (u16*)p; p += nW * 2;          //  16 MiB
    u16* WvH = (u16*)p; p += nW * 2;          //  16 MiB
    u16* Qa = (u16*)p; p += nAll * 2;         //  64 MiB
    u16* Ka = (u16*)p; p += nAll * 2;         //  64 MiB
    u16* VTa = (u16*)p; p += nAll * 2;        //  64 MiB
    float* S = (float*)p; p += nS * 4;        // 128 MiB
    u16* P = (u16*)p; p += nS * 2;            //  64 MiB

    const dim3 blk256(256), blk512(512);
    const float inv_sqrt_c = 1.0f / 32.0f;

    cast_f32_f16<<<dim3((unsigned)(nData / 4 / 256)), blk256, 0, stream>>>(data, dataH, (int)(nData / 4));
    cast_f32_f16<<<dim3((unsigned)(nW / 4 / 256)), blk256, 0, stream>>>(Wq, WqH, (int)(nW / 4));
    cast_f32_f16<<<dim3((unsigned)(nW / 4 / 256)), blk256, 0, stream>>>(Wk, WkH, (int)(nW / 4));
    cast_f32_f16<<<dim3((unsigned)(nW / 4 / 256)), blk256, 0, stream>>>(Wv, WvH, (int)(nW / 4));

    // Q/K projections: [4096,1024] x [8192,1024]^T -> fp16 [4096,8192]
    gemm256<0><<<dim3(HC / 256, BT / 256, 1), blk512, 0, stream>>>(
        dataH, WqH, Qa, C, C, HC, 0, 0, 0, 0, 0, 0, C, 1.0f);
    gemm256<0><<<dim3(HC / 256, BT / 256, 1), blk512, 0, stream>>>(
        dataH, WkH, Ka, C, C, HC, 0, 0, 0, 0, 0, 0, C, 1.0f);

    // V^T directly: VT[z][c][t] = sum_k Wv[h][c][k] data[b][t][k]
    gemm256<0><<<dim3(T / 256, C / 256, B * H), blk512, 0, stream>>>(
        WvH, dataH, VTa, C, C, T,
        0, (long)C * C,               // A (Wv): h-stride
        (long)T * C, 0,               // B (data): b-stride
        (long)8 * C * T, (long)C * T, // C (VT): z-major
        C, 1.0f);

    // scores = Q K^T / sqrt(C), causal tiles, fp32
    gemm256<2><<<dim3(T / 256, T / 256, B * H), blk512, 0, stream>>>(
        Qa, Ka, S,
        HC, HC, T,
        (long)T * HC, C,
        (long)T * HC, C,
        (long)8 * T * T, (long)T * T,
        C, inv_sqrt_c);

    softmax_causal<<<dim3(T, B * H), blk256, 0, stream>>>(S, P);

    // out[b,t,h*C+d] = sum_s P[t,s] VT[d,s], causal K-limit
    gemm256<3><<<dim3(C / 256, T / 256, B * H), blk512, 0, stream>>>(
        P, VTa, out,
        T, T, HC,
        (long)8 * T * T, (long)T * T,
        (long)8 * C * T, (long)C * T,
        (long)T * HC, C,
        T, 1.0f);
}

// Round 7
// 433.890 us; speedup vs baseline: 1.0756x; 1.0756x over previous
//
#include <hip/hip_runtime.h>
#include <hip/hip_fp16.h>

// ---------------------------------------------------------------------------
// Heads: per-head QKV projections + causal attention, B=4 T=1024 C=1024 H=8.
// Round 7: dispatch-schedule optimization. GEMM core = round-5 verbatim
// (~93% of the m248 K=1024 same-shape reference). 5 dispatches:
//   cast_all -> mega<PROJ> (Q,K,VT merged; 1536 blocks, 6.0 exact rounds)
//   -> mega<QK> (320 causal-active tiles only, fp16 S out)
//   -> softmax16 (fp16 in/out) -> mega<PV> (LPT: long-K blocks first).
// All GEMM grids XCD-chunk swizzled (T1, bijective; grids %8==0).
// ---------------------------------------------------------------------------

typedef unsigned short u16;
typedef _Float16 f16x8 __attribute__((ext_vector_type(8)));
typedef float f32x4 __attribute__((ext_vector_type(4)));

__device__ __forceinline__ u16 f2h(float f) {
    union { __half h; u16 u; } cv;
    cv.h = __float2half(f);
    return cv.u;
}
__device__ __forceinline__ float h2f(u16 u) {
    union { __half h; u16 u; } cv;
    cv.u = u;
    return __half2float(cv.h);
}

// global -> LDS direct copy, 16B/lane (wave-uniform LDS base + lane*16).
__device__ __forceinline__ void gload_lds16(const u16* g, const u16* lds_base, unsigned off_bytes) {
    unsigned a32 = (unsigned)(uintptr_t)((const char*)lds_base + off_bytes);
    a32 = __builtin_amdgcn_readfirstlane(a32);
    __builtin_amdgcn_global_load_lds(
        (const __attribute__((address_space(1))) void*)(uintptr_t)g,
        (__attribute__((address_space(3))) void*)a32,
        16, 0, 0);
}

#define M_PROJ 0
#define M_QK 1
#define M_PV 2

// ---------------------------------------------------------------------------
// mega<MODE>: 256x256 tile, BK=64, 8 waves (2Mx4N), per-wave 128x64 out.
// D = scale * A x Bt^T (both operands [rows][K] fp16). Round-5 inner loop.
// MODE selects block->tile decode + operands + output dtype:
//   PROJ: 1536 blocks = Qproj(512) | Kproj(512) | VT(512), fp16 out
//   QK:   320 blocks = 32 z x 10 lower-triangle tiles, fp16 out, scale 1/32
//   PV:   512 blocks = 32 z x 16 tiles, fp32 out, causal K-limit + LPT order
// ---------------------------------------------------------------------------
template <int MODE>
__global__ __launch_bounds__(512, 2) void mega(
    const u16* __restrict__ dataH, const u16* __restrict__ WqH,
    const u16* __restrict__ WkH, const u16* __restrict__ WvH,
    u16* __restrict__ Qa, u16* __restrict__ Ka, u16* __restrict__ VTa,
    u16* __restrict__ S16, const u16* __restrict__ P16,
    float* __restrict__ outF)
{
    const int C = 1024, T = 1024, HC = 8192;
    const int nb = (MODE == M_PROJ ? 1536 : MODE == M_QK ? 320 : 512);
    const int chunk = nb >> 3;
    const int phys = blockIdx.x;
    const int o = (phys & 7) * chunk + (phys >> 3);   // XCD-chunked remap

    const u16 *Ab, *Bb;
    int lda, ldb, ldc, NT, tile_m, tile_n;
    float scale = 1.0f;
    u16* out16 = nullptr;
    float* out32 = nullptr;

    if (MODE == M_PROJ) {
        const int g = o >> 9, r = o & 511;
        if (g < 2) {       // Q / K projection: [4096,1024] x [8192,1024]^T
            const int s = r >> 6, ww = r & 63;   // 8x8 super-tiles for L2
            tile_n = (s & 3) * 8 + (ww & 7);
            tile_m = (s >> 2) * 8 + (ww >> 3);
            Ab = dataH + (size_t)tile_m * 256 * C;
            Bb = (g ? WkH : WqH) + (size_t)tile_n * 256 * C;
            lda = C; ldb = C; ldc = HC;
            out16 = g ? Ka : Qa;
            NT = 16;
        } else {           // VT[z][c][t] = sum_k Wv[h][c][k] data[b][t][k]
            const int vz = r >> 4, rem = r & 15;
            tile_n = rem & 3; tile_m = rem >> 2;
            Ab = WvH + (size_t)(vz & 7) * C * C + (size_t)tile_m * 256 * C;
            Bb = dataH + (size_t)(vz >> 3) * T * C + (size_t)tile_n * 256 * C;
            lda = C; ldb = C; ldc = T;
            out16 = VTa + (size_t)vz * C * T;
            NT = 16;
        }
    } else if (MODE == M_QK) {
        const int qz = o / 10, j = o - qz * 10;
        tile_m = (j >= 1) + (j >= 3) + (j >= 6);
        tile_n = j - (tile_m == 0 ? 0 : tile_m == 1 ? 1 : tile_m == 2 ? 3 : 6);
        const size_t zo = (size_t)(qz >> 3) * T * HC + (size_t)(qz & 7) * C;
        Ab = Qa + zo + (size_t)tile_m * 256 * HC;
        Bb = Ka + zo + (size_t)tile_n * 256 * HC;
        lda = HC; ldb = HC; ldc = T;
        out16 = S16 + (size_t)qz * T * T;
        scale = 1.0f / 32.0f;
        NT = 16;
    } else {               // PV: out = P x VT^T, causal K-limit, LPT order
        const int x = o & 3, y = (o >> 2) & 3, pz = o >> 4;
        tile_m = 3 - y;    // long-K blocks dispatch first per XCD queue
        tile_n = x;
        Ab = P16 + (size_t)pz * T * T + (size_t)tile_m * 256 * T;
        Bb = VTa + (size_t)pz * C * T + (size_t)tile_n * 256 * T;
        lda = T; ldb = T; ldc = HC;
        out32 = outF + (size_t)(pz >> 3) * T * HC + (size_t)(pz & 7) * C;
        NT = (tile_m + 1) * 4;   // Kend/64 in {4,8,12,16}
    }

    __shared__ u16 lds[8 * 8192];  // halfbase(db,mat,ks) = ((db<<2)|(mat<<1)|ks)*8192

    const int t = threadIdx.x, w = t >> 6, l = t & 63;
    const int wm = w >> 2, wn = w & 3;
    const int frow = l & 15, fch = l >> 4;

    // staging constants: linear chunk clin -> (row, chunk^((row>>1)&3)) involution
    const int clin = w * 64 + l;
    const int srow = clin >> 2;
    const int sch = (clin & 3) ^ ((clin >> 3) & 3);
    const long eA = (long)srow * lda + sch * 8;
    const long eB = (long)srow * ldb + sch * 8;

    f32x4 acc[8][4] = {};
    f16x8 af[4], bf[4];

#define STAGE(DB, MAT, KS, TT) do {                                            \
        const u16* g_ = (MAT == 0 ? Ab + (size_t)(TT) * 64 + (KS) * 32 + eA    \
                                  : Bb + (size_t)(TT) * 64 + (KS) * 32 + eB);  \
        const u16* hb_ = lds + ((((DB) << 2) | ((MAT) << 1) | (KS)) << 13);    \
        gload_lds16(g_, hb_, (unsigned)(w * 64 * 16));                         \
        gload_lds16(g_ + (size_t)128 * (MAT == 0 ? lda : ldb), hb_,            \
                    (unsigned)((512 + w * 64) * 16));                          \
    } while (0)

#define RD(DB, MAT, KS, ROW)                                                   \
    (*(const f16x8*)((const char*)(lds + ((((DB) << 2) | ((MAT) << 1) | (KS)) << 13)) + \
                     ((unsigned)((ROW) * 64 + fch * 16) ^ ((((ROW) >> 1) & 3) << 4))))

#define VM6 do { asm volatile("s_waitcnt vmcnt(6)"); \
                 __builtin_amdgcn_sched_barrier(0); } while (0)
#define VM0 do { asm volatile("s_waitcnt vmcnt(0)"); \
                 __builtin_amdgcn_sched_barrier(0); } while (0)
#define NOPW ((void)0)

#define PH(DB, KS, MH, WAITC, ...) do {                                        \
        if ((MH) == 0) {                                                       \
            _Pragma("unroll") for (int ni = 0; ni < 4; ++ni)                   \
                bf[ni] = RD(DB, 1, KS, wn * 64 + ni * 16 + frow);              \
        }                                                                      \
        _Pragma("unroll") for (int m4 = 0; m4 < 4; ++m4)                       \
            af[m4] = RD(DB, 0, KS, wm * 128 + ((MH) * 4 + m4) * 16 + frow);    \
        __VA_ARGS__;                                                           \
        __builtin_amdgcn_sched_barrier(0);                                     \
        __builtin_amdgcn_s_barrier();                                          \
        asm volatile("s_waitcnt lgkmcnt(0)");                                  \
        __builtin_amdgcn_sched_barrier(0);                                     \
        __builtin_amdgcn_s_setprio(1);                                         \
        _Pragma("unroll") for (int m4 = 0; m4 < 4; ++m4)                       \
            _Pragma("unroll") for (int ni = 0; ni < 4; ++ni)                   \
                acc[(MH) * 4 + m4][ni] = __builtin_amdgcn_mfma_f32_16x16x32_f16( \
                    af[m4], bf[ni], acc[(MH) * 4 + m4][ni], 0, 0, 0);          \
        __builtin_amdgcn_s_setprio(0);                                         \
        __builtin_amdgcn_sched_barrier(0);                                     \
        WAITC;                                                                 \
        __builtin_amdgcn_s_barrier();                                          \
    } while (0)

    // prologue: tile0 (4 halves) + tile1 (3 halves; A-ks1 issued at p0)
    STAGE(0, 1, 0, 0); STAGE(0, 0, 0, 0); STAGE(0, 1, 1, 0); STAGE(0, 0, 1, 0);
    STAGE(1, 1, 0, 1); STAGE(1, 0, 0, 1); STAGE(1, 1, 1, 1);
    VM6;
    __builtin_amdgcn_s_barrier();

    for (int tt = 0; tt < NT; tt += 2) {
        const bool more = (tt + 2) < NT;
        PH(0, 0, 0, NOPW, STAGE(1, 0, 1, tt + 1));              // p0
        PH(0, 0, 1, NOPW, if (more) STAGE(0, 1, 0, tt + 2));    // p1
        PH(0, 1, 0, NOPW, if (more) STAGE(0, 0, 0, tt + 2));    // p2
        PH(0, 1, 1, if (more) VM6; else VM0,
                    if (more) STAGE(0, 1, 1, tt + 2));          // p3
        PH(1, 0, 0, NOPW, if (more) STAGE(0, 0, 1, tt + 2));    // p4
        PH(1, 0, 1, NOPW, if (more) STAGE(1, 1, 0, tt + 3));    // p5
        PH(1, 1, 0, NOPW, if (more) STAGE(1, 0, 0, tt + 3));    // p6
        PH(1, 1, 1, if (more) VM6; else VM0,
                    if (more) STAGE(1, 1, 1, tt + 3));          // p7
    }
#undef PH
#undef RD
#undef STAGE

    // epilogue: C/D layout col = l&15, row = (l>>4)*4 + r
    const int r0 = (l >> 4) * 4, cc = l & 15;
#pragma unroll
    for (int mi = 0; mi < 8; ++mi) {
#pragma unroll
        for (int r = 0; r < 4; ++r) {
            size_t grow = (size_t)(tile_m * 256 + wm * 128 + mi * 16 + r0 + r);
#pragma unroll
            for (int ni = 0; ni < 4; ++ni) {
                int gcol = tile_n * 256 + wn * 64 + ni * 16 + cc;
                float v = acc[mi][ni][r] * scale;
                if (MODE == M_PV)
                    out32[grow * ldc + gcol] = v;
                else
                    out16[grow * ldc + gcol] = f2h(v);
            }
        }
    }
}

// ---------------------------------------------------------------------------
// single-pass causal softmax, fp16 S -> fp16 P. Row in registers (4/thread);
// zero-fill to round256(t+1) exactly matches PV's causal K-limit reads.
// ---------------------------------------------------------------------------
__global__ __launch_bounds__(256) void softmax16(
    const u16* __restrict__ S, u16* __restrict__ P)
{
    const int T = 1024;
    const int tq = blockIdx.x, z = blockIdx.y;
    const u16* row = S + ((size_t)z * T + tq) * T;
    u16* prow = P + ((size_t)z * T + tq) * T;
    const int n = tq + 1, tid = threadIdx.x, i0 = tid * 4;
    const int nw = ((tq >> 8) + 1) << 8;

    ushort4 v = ((const ushort4*)row)[tid];
    float e0 = (i0 + 0 < n) ? h2f(v.x) : -1e30f;
    float e1 = (i0 + 1 < n) ? h2f(v.y) : -1e30f;
    float e2 = (i0 + 2 < n) ? h2f(v.z) : -1e30f;
    float e3 = (i0 + 3 < n) ? h2f(v.w) : -1e30f;

    float m = fmaxf(fmaxf(e0, e1), fmaxf(e2, e3));
#pragma unroll
    for (int o = 1; o < 64; o <<= 1) m = fmaxf(m, __shfl_xor(m, o));
    __shared__ float red[4];
    if ((tid & 63) == 0) red[tid >> 6] = m;
    __syncthreads();
    m = fmaxf(fmaxf(red[0], red[1]), fmaxf(red[2], red[3]));

    float p0 = __expf(e0 - m), p1 = __expf(e1 - m);
    float p2 = __expf(e2 - m), p3 = __expf(e3 - m);
    float s = p0 + p1 + p2 + p3;
#pragma unroll
    for (int o = 1; o < 64; o <<= 1) s += __shfl_xor(s, o);
    __shared__ float red2[4];
    if ((tid & 63) == 0) red2[tid >> 6] = s;
    __syncthreads();
    const float inv = 1.0f / (red2[0] + red2[1] + red2[2] + red2[3]);

    if (i0 < nw) {
        ushort4 o4;
        o4.x = f2h(p0 * inv); o4.y = f2h(p1 * inv);
        o4.z = f2h(p2 * inv); o4.w = f2h(p3 * inv);
        ((ushort4*)prow)[tid] = o4;
    }
}

// all four f32->f16 casts in one dispatch; dst buffers are ws-contiguous.
__global__ __launch_bounds__(256) void cast_all(
    const float* __restrict__ d0, const float* __restrict__ w1,
    const float* __restrict__ w2, const float* __restrict__ w3,
    u16* __restrict__ dst)
{
    const int n0 = 1048576, nW = 2097152;          // float4 counts
    for (int i = blockIdx.x * 256 + threadIdx.x; i < 7340032; i += 524288) {
        float4 v;
        if (i < n0)               v = ((const float4*)d0)[i];
        else if (i < n0 + nW)     v = ((const float4*)w1)[i - n0];
        else if (i < n0 + 2 * nW) v = ((const float4*)w2)[i - n0 - nW];
        else                      v = ((const float4*)w3)[i - n0 - 2 * nW];
        ushort4 o4;
        o4.x = f2h(v.x); o4.y = f2h(v.y); o4.z = f2h(v.z); o4.w = f2h(v.w);
        ((ushort4*)dst)[i] = o4;
    }
}

extern "C" void kernel_launch(void* const* d_in, const int* in_sizes, int n_in,
                              void* d_out, int out_size, void* d_ws, size_t ws_size,
                              hipStream_t stream)
{
    (void)in_sizes; (void)n_in; (void)out_size; (void)ws_size;
    const int B = 4, T = 1024, C = 1024, H = 8;
    const int BT = B * T, HC = H * C;

    const float* data = (const float*)d_in[0];
    const float* Wq = (const float*)d_in[1];
    const float* Wk = (const float*)d_in[2];
    const float* Wv = (const float*)d_in[3];
    float* out = (float*)d_out;

    // workspace layout (376 MiB of 512 MiB); dataH..WvH contiguous for cast_all
    char* p = (char*)d_ws;
    const size_t nData = (size_t)BT * C;      // 4M
    const size_t nW = (size_t)H * C * C;      // 8M
    const size_t nAll = (size_t)BT * HC;      // 32M
    const size_t nS = (size_t)B * H * T * T;  // 32M
    u16* dataH = (u16*)p; p += nData * 2;     //   8 MiB
    u16* WqH = (u16*)p; p += nW * 2;          //  16 MiB
    u16* WkH = (u16*)p; p += nW * 2;          //  16 MiB
    u16* WvH = (u16*)p; p += nW * 2;          //  16 MiB
    u16* Qa = (u16*)p; p += nAll * 2;         //  64 MiB
    u16* Ka = (u16*)p; p += nAll * 2;         //  64 MiB
    u16* VTa = (u16*)p; p += nAll * 2;        //  64 MiB
    u16* S16 = (u16*)p; p += nS * 2;          //  64 MiB
    u16* P16 = (u16*)p; p += nS * 2;          //  64 MiB

    cast_all<<<dim3(2048), dim3(256), 0, stream>>>(data, Wq, Wk, Wv, dataH);

    mega<M_PROJ><<<dim3(1536), dim3(512), 0, stream>>>(
        dataH, WqH, WkH, WvH, Qa, Ka, VTa, S16, P16, out);

    mega<M_QK><<<dim3(320), dim3(512), 0, stream>>>(
        dataH, WqH, WkH, WvH, Qa, Ka, VTa, S16, P16, out);

    softmax16<<<dim3(T, B * H), dim3(256), 0, stream>>>(S16, P16);

    mega<M_PV><<<dim3(512), dim3(512), 0, stream>>>(
        dataH, WqH, WkH, WvH, Qa, Ka, VTa, S16, P16, out);
}

// Round 8
// 384.766 us; speedup vs baseline: 1.2129x; 1.1277x over previous
//
#include <hip/hip_runtime.h>
#include <hip/hip_fp16.h>

// ---------------------------------------------------------------------------
// Heads: per-head QKV projections + causal attention, B=4 T=1024 C=1024 H=8.
// Round 8: (a) M-fold: scores = X (Wq^T Wk) X^T -- precompute MT_h = (Wq^T Wk)^T
// (17 GF) and drop the K-projection (69 GF); QK's B-operand becomes X itself.
// (b) PV pairing: each block runs two K-loops (tile_m pairs (3,0)/(2,1)) ->
// 256 uniform NT=20 blocks = exactly 1 fill at 1 block/CU.
// (c) merged cast+transpose setup dispatch.
// GEMM core (256x256, BK=64, 8-phase counted-vmcnt) = round-5 verbatim.
// Dispatches: cast_setup -> MT(128) -> {Q'+VT}(1024) -> QK(320) -> SM -> PV(256).
// ---------------------------------------------------------------------------

typedef unsigned short u16;
typedef _Float16 f16x8 __attribute__((ext_vector_type(8)));
typedef float f32x4 __attribute__((ext_vector_type(4)));

__device__ __forceinline__ u16 f2h(float f) {
    union { __half h; u16 u; } cv;
    cv.h = __float2half(f);
    return cv.u;
}
__device__ __forceinline__ float h2f(u16 u) {
    union { __half h; u16 u; } cv;
    cv.u = u;
    return __half2float(cv.h);
}

// global -> LDS direct copy, 16B/lane (wave-uniform LDS base + lane*16).
__device__ __forceinline__ void gload_lds16(const u16* g, const u16* lds_base, unsigned off_bytes) {
    unsigned a32 = (unsigned)(uintptr_t)((const char*)lds_base + off_bytes);
    a32 = __builtin_amdgcn_readfirstlane(a32);
    __builtin_amdgcn_global_load_lds(
        (const __attribute__((address_space(1))) void*)(uintptr_t)g,
        (__attribute__((address_space(3))) void*)a32,
        16, 0, 0);
}

#define M_MT 0
#define M_PROJ 1
#define M_QK 2
#define M_PV 3

// ---------------------------------------------------------------------------
// mega<MODE>: 256x256 tile, BK=64, 8 waves (2Mx4N), per-wave 128x64 out.
// D = scale * A x Bt^T (operands [rows][K] fp16). Round-5 8-phase inner loop.
//   MT:   128 blocks: MT_h[c'][c] = sum_d WkT[c'][d] WqT[c][d], fp16 out
//   PROJ: 1024 = Q'(512: X x MT_h) | VT(512: Wv x X), fp16 out
//   QK:   320 = 32 z x 10 causal tiles: Q' x X^T, fp16 out, scale 1/32
//   PV:   256 blocks x 2 passes (tile_m pairs (3,0),(2,1)): P x VT^T, fp32 out
// ---------------------------------------------------------------------------
template <int MODE>
__global__ __launch_bounds__(512, 2) void mega(
    const u16* __restrict__ dataH, const u16* __restrict__ WvH,
    const u16* __restrict__ WqT, const u16* __restrict__ WkT,
    u16* __restrict__ MTp, u16* __restrict__ Qp, u16* __restrict__ VTa,
    u16* __restrict__ S16, const u16* __restrict__ P16,
    float* __restrict__ outF)
{
    const int C = 1024, T = 1024, HC = 8192;
    const int nb = (MODE == M_MT ? 128 : MODE == M_PROJ ? 1024 :
                    MODE == M_QK ? 320 : 256);
    const int chunk = nb >> 3;
    const int phys = blockIdx.x;
    const int o = (phys & 7) * chunk + (phys >> 3);   // XCD-chunked remap

    __shared__ u16 lds[8 * 8192];  // halfbase(db,mat,ks) = ((db<<2)|(mat<<1)|ks)*8192

    const int t = threadIdx.x, w = t >> 6, l = t & 63;
    const int wm = w >> 2, wn = w & 3;
    const int frow = l & 15, fch = l >> 4;
    const int clin = w * 64 + l;
    const int srow = clin >> 2;
    const int sch = (clin & 3) ^ ((clin >> 3) & 3);

    const int NPASS = (MODE == M_PV) ? 2 : 1;

    for (int pass = 0; pass < NPASS; ++pass) {
        const u16 *Ab, *Bb;
        int lda, ldb, ldc, NT, tile_m, tile_n;
        float scale = 1.0f;
        u16* out16 = nullptr;
        float* out32 = nullptr;

        if (MODE == M_MT) {
            const int h = o >> 4, r = o & 15;
            tile_m = r >> 2; tile_n = r & 3;
            Ab = WkT + (size_t)h * C * C + (size_t)tile_m * 256 * C;
            Bb = WqT + (size_t)h * C * C + (size_t)tile_n * 256 * C;
            lda = C; ldb = C; ldc = C;
            out16 = MTp + (size_t)h * C * C;
            NT = 16;
        } else if (MODE == M_PROJ) {
            const int g = o >> 9, r = o & 511;
            if (g == 0) {   // Q'[t][h*C+c'] = sum_c X[t][c] MT_h[c'][c]
                const int s = r >> 6, ww = r & 63;   // 8x8 super-tiles
                tile_n = (s & 3) * 8 + (ww & 7);     // 0..31 (h = n>>2)
                tile_m = (s >> 2) * 8 + (ww >> 3);   // 0..15
                Ab = dataH + (size_t)tile_m * 256 * C;
                Bb = MTp + (size_t)(tile_n >> 2) * C * C + (size_t)(tile_n & 3) * 256 * C;
                lda = C; ldb = C; ldc = HC;
                out16 = Qp;
                NT = 16;
            } else {        // VT[z][c][t] = sum_k Wv[h][c][k] X[b][t][k]
                const int vz = r >> 4, rem = r & 15;
                tile_n = rem & 3; tile_m = rem >> 2;
                Ab = WvH + (size_t)(vz & 7) * C * C + (size_t)tile_m * 256 * C;
                Bb = dataH + (size_t)(vz >> 3) * T * C + (size_t)tile_n * 256 * C;
                lda = C; ldb = C; ldc = T;
                out16 = VTa + (size_t)vz * C * T;
                NT = 16;
            }
        } else if (MODE == M_QK) {
            const int qz = o / 10, j = o - qz * 10;
            tile_m = (j >= 1) + (j >= 3) + (j >= 6);
            tile_n = j - (tile_m == 0 ? 0 : tile_m == 1 ? 1 : tile_m == 2 ? 3 : 6);
            Ab = Qp + (size_t)(qz >> 3) * T * HC + (size_t)(qz & 7) * C
                    + (size_t)tile_m * 256 * HC;
            Bb = dataH + (size_t)(qz >> 3) * T * C + (size_t)tile_n * 256 * C;
            lda = HC; ldb = C; ldc = T;
            out16 = S16 + (size_t)qz * T * T;
            scale = 1.0f / 32.0f;
            NT = 16;
        } else {            // PV, paired: pass0 m in {3,2}, pass1 m in {0,1}
            const int pz = o >> 3, j = o & 7, x = j & 3, hi = j >> 2;
            tile_m = (pass == 0) ? (hi ? 2 : 3) : (hi ? 1 : 0);
            tile_n = x;
            Ab = P16 + (size_t)pz * T * T + (size_t)tile_m * 256 * T;
            Bb = VTa + (size_t)pz * C * T + (size_t)tile_n * 256 * T;
            lda = T; ldb = T; ldc = HC;
            out32 = outF + (size_t)(pz >> 3) * T * HC + (size_t)(pz & 7) * C;
            NT = (tile_m + 1) * 4;   // 4..16
        }

        const long eA = (long)srow * lda + sch * 8;
        const long eB = (long)srow * ldb + sch * 8;

        f32x4 acc[8][4] = {};
        f16x8 af[4], bf[4];

#define STAGE(DB, MAT, KS, TT) do {                                            \
        const u16* g_ = (MAT == 0 ? Ab + (size_t)(TT) * 64 + (KS) * 32 + eA    \
                                  : Bb + (size_t)(TT) * 64 + (KS) * 32 + eB);  \
        const u16* hb_ = lds + ((((DB) << 2) | ((MAT) << 1) | (KS)) << 13);    \
        gload_lds16(g_, hb_, (unsigned)(w * 64 * 16));                         \
        gload_lds16(g_ + (size_t)128 * (MAT == 0 ? lda : ldb), hb_,            \
                    (unsigned)((512 + w * 64) * 16));                          \
    } while (0)

#define RD(DB, MAT, KS, ROW)                                                   \
    (*(const f16x8*)((const char*)(lds + ((((DB) << 2) | ((MAT) << 1) | (KS)) << 13)) + \
                     ((unsigned)((ROW) * 64 + fch * 16) ^ ((((ROW) >> 1) & 3) << 4))))

#define VM6 do { asm volatile("s_waitcnt vmcnt(6)"); \
                 __builtin_amdgcn_sched_barrier(0); } while (0)
#define VM0 do { asm volatile("s_waitcnt vmcnt(0)"); \
                 __builtin_amdgcn_sched_barrier(0); } while (0)
#define NOPW ((void)0)

#define PH(DB, KS, MH, WAITC, ...) do {                                        \
        if ((MH) == 0) {                                                       \
            _Pragma("unroll") for (int ni = 0; ni < 4; ++ni)                   \
                bf[ni] = RD(DB, 1, KS, wn * 64 + ni * 16 + frow);              \
        }                                                                      \
        _Pragma("unroll") for (int m4 = 0; m4 < 4; ++m4)                       \
            af[m4] = RD(DB, 0, KS, wm * 128 + ((MH) * 4 + m4) * 16 + frow);    \
        __VA_ARGS__;                                                           \
        __builtin_amdgcn_sched_barrier(0);                                     \
        __builtin_amdgcn_s_barrier();                                          \
        asm volatile("s_waitcnt lgkmcnt(0)");                                  \
        __builtin_amdgcn_sched_barrier(0);                                     \
        __builtin_amdgcn_s_setprio(1);                                         \
        _Pragma("unroll") for (int m4 = 0; m4 < 4; ++m4)                       \
            _Pragma("unroll") for (int ni = 0; ni < 4; ++ni)                   \
                acc[(MH) * 4 + m4][ni] = __builtin_amdgcn_mfma_f32_16x16x32_f16( \
                    af[m4], bf[ni], acc[(MH) * 4 + m4][ni], 0, 0, 0);          \
        __builtin_amdgcn_s_setprio(0);                                         \
        __builtin_amdgcn_sched_barrier(0);                                     \
        WAITC;                                                                 \
        __builtin_amdgcn_s_barrier();                                          \
    } while (0)

        // prologue: tile0 (4 halves) + tile1 (3 halves; A-ks1 issued at p0)
        STAGE(0, 1, 0, 0); STAGE(0, 0, 0, 0); STAGE(0, 1, 1, 0); STAGE(0, 0, 1, 0);
        STAGE(1, 1, 0, 1); STAGE(1, 0, 0, 1); STAGE(1, 1, 1, 1);
        VM6;
        __builtin_amdgcn_s_barrier();

        for (int tt = 0; tt < NT; tt += 2) {
            const bool more = (tt + 2) < NT;
            PH(0, 0, 0, NOPW, STAGE(1, 0, 1, tt + 1));              // p0
            PH(0, 0, 1, NOPW, if (more) STAGE(0, 1, 0, tt + 2));    // p1
            PH(0, 1, 0, NOPW, if (more) STAGE(0, 0, 0, tt + 2));    // p2
            PH(0, 1, 1, if (more) VM6; else VM0,
                        if (more) STAGE(0, 1, 1, tt + 2));          // p3
            PH(1, 0, 0, NOPW, if (more) STAGE(0, 0, 1, tt + 2));    // p4
            PH(1, 0, 1, NOPW, if (more) STAGE(1, 1, 0, tt + 3));    // p5
            PH(1, 1, 0, NOPW, if (more) STAGE(1, 0, 0, tt + 3));    // p6
            PH(1, 1, 1, if (more) VM6; else VM0,
                        if (more) STAGE(1, 1, 1, tt + 3));          // p7
        }
#undef PH
#undef RD
#undef STAGE
#undef VM6
#undef VM0
#undef NOPW

        // epilogue: C/D layout col = l&15, row = (l>>4)*4 + r
        const int r0 = (l >> 4) * 4, cc = l & 15;
#pragma unroll
        for (int mi = 0; mi < 8; ++mi) {
#pragma unroll
            for (int r = 0; r < 4; ++r) {
                size_t grow = (size_t)(tile_m * 256 + wm * 128 + mi * 16 + r0 + r);
#pragma unroll
                for (int ni = 0; ni < 4; ++ni) {
                    int gcol = tile_n * 256 + wn * 64 + ni * 16 + cc;
                    float v = acc[mi][ni][r] * scale;
                    if (MODE == M_PV)
                        out32[grow * ldc + gcol] = v;
                    else
                        out16[grow * ldc + gcol] = f2h(v);
                }
            }
        }
    }
}

// ---------------------------------------------------------------------------
// single-pass causal softmax, fp16 S -> fp16 P; zero-fill to round256(t+1).
// ---------------------------------------------------------------------------
__global__ __launch_bounds__(256) void softmax16(
    const u16* __restrict__ S, u16* __restrict__ P)
{
    const int T = 1024;
    const int tq = blockIdx.x, z = blockIdx.y;
    const u16* row = S + ((size_t)z * T + tq) * T;
    u16* prow = P + ((size_t)z * T + tq) * T;
    const int n = tq + 1, tid = threadIdx.x, i0 = tid * 4;
    const int nw = ((tq >> 8) + 1) << 8;

    ushort4 v = ((const ushort4*)row)[tid];
    float e0 = (i0 + 0 < n) ? h2f(v.x) : -1e30f;
    float e1 = (i0 + 1 < n) ? h2f(v.y) : -1e30f;
    float e2 = (i0 + 2 < n) ? h2f(v.z) : -1e30f;
    float e3 = (i0 + 3 < n) ? h2f(v.w) : -1e30f;

    float m = fmaxf(fmaxf(e0, e1), fmaxf(e2, e3));
#pragma unroll
    for (int o = 1; o < 64; o <<= 1) m = fmaxf(m, __shfl_xor(m, o));
    __shared__ float red[4];
    if ((tid & 63) == 0) red[tid >> 6] = m;
    __syncthreads();
    m = fmaxf(fmaxf(red[0], red[1]), fmaxf(red[2], red[3]));

    float p0 = __expf(e0 - m), p1 = __expf(e1 - m);
    float p2 = __expf(e2 - m), p3 = __expf(e3 - m);
    float s = p0 + p1 + p2 + p3;
#pragma unroll
    for (int o = 1; o < 64; o <<= 1) s += __shfl_xor(s, o);
    __shared__ float red2[4];
    if ((tid & 63) == 0) red2[tid >> 6] = s;
    __syncthreads();
    const float inv = 1.0f / (red2[0] + red2[1] + red2[2] + red2[3]);

    if (i0 < nw) {
        ushort4 o4;
        o4.x = f2h(p0 * inv); o4.y = f2h(p1 * inv);
        o4.z = f2h(p2 * inv); o4.w = f2h(p3 * inv);
        ((ushort4*)prow)[tid] = o4;
    }
}

// ---------------------------------------------------------------------------
// setup: z<16 -> per-head transpose-cast of Wq/Wk (f32 [d][c] -> f16 [c][d]);
// z==16 -> data cast; z==17 -> Wv cast. grid (32,32,18), block (32,8).
// ---------------------------------------------------------------------------
__global__ __launch_bounds__(256) void cast_setup(
    const float* __restrict__ data, const float* __restrict__ Wq,
    const float* __restrict__ Wk, const float* __restrict__ Wv,
    u16* __restrict__ dataH, u16* __restrict__ WqT,
    u16* __restrict__ WkT, u16* __restrict__ WvH)
{
    const int z = blockIdx.z, tx = threadIdx.x, ty = threadIdx.y;
    if (z < 16) {
        const int h = z & 7;
        const float* src = ((z >> 3) ? Wk : Wq) + (size_t)h * 1048576;
        u16* dst = ((z >> 3) ? WkT : WqT) + (size_t)h * 1048576;
        const int r0 = blockIdx.y * 32, c0 = blockIdx.x * 32;
        __shared__ float tile[32][33];
        for (int i = ty; i < 32; i += 8)
            tile[i][tx] = src[(size_t)(r0 + i) * 1024 + c0 + tx];
        __syncthreads();
        for (int i = ty; i < 32; i += 8)
            dst[(size_t)(c0 + i) * 1024 + r0 + tx] = f2h(tile[tx][i]);
    } else {
        const int tid = ty * 32 + tx;
        const int bid = blockIdx.y * 32 + blockIdx.x;   // 0..1023
        const int reps = (z == 16) ? 4 : 8;             // 1M / 2M float4
        const float* src = (z == 16) ? data : Wv;
        u16* dst = (z == 16) ? dataH : WvH;
        for (int k2 = 0; k2 < reps; ++k2) {
            int i = (k2 * 1024 + bid) * 256 + tid;
            float4 v = ((const float4*)src)[i];
            ushort4 o4;
            o4.x = f2h(v.x); o4.y = f2h(v.y); o4.z = f2h(v.z); o4.w = f2h(v.w);
            ((ushort4*)dst)[i] = o4;
        }
    }
}

extern "C" void kernel_launch(void* const* d_in, const int* in_sizes, int n_in,
                              void* d_out, int out_size, void* d_ws, size_t ws_size,
                              hipStream_t stream)
{
    (void)in_sizes; (void)n_in; (void)out_size; (void)ws_size;
    const int B = 4, T = 1024, C = 1024, H = 8;
    const int BT = B * T, HC = H * C;

    const float* data = (const float*)d_in[0];
    const float* Wq = (const float*)d_in[1];
    const float* Wk = (const float*)d_in[2];
    const float* Wv = (const float*)d_in[3];
    float* out = (float*)d_out;

    // workspace (328 MiB of 512 MiB)
    char* p = (char*)d_ws;
    const size_t nData = (size_t)BT * C;      // 4M
    const size_t nW = (size_t)H * C * C;      // 8M
    const size_t nAll = (size_t)BT * HC;      // 32M
    const size_t nS = (size_t)B * H * T * T;  // 32M
    u16* dataH = (u16*)p; p += nData * 2;     //   8 MiB
    u16* WvH = (u16*)p; p += nW * 2;          //  16 MiB
    u16* WqT = (u16*)p; p += nW * 2;          //  16 MiB
    u16* WkT = (u16*)p; p += nW * 2;          //  16 MiB
    u16* MTp = (u16*)p; p += nW * 2;          //  16 MiB
    u16* Qp = (u16*)p; p += nAll * 2;         //  64 MiB
    u16* VTa = (u16*)p; p += nAll * 2;        //  64 MiB
    u16* S16 = (u16*)p; p += nS * 2;          //  64 MiB
    u16* P16 = (u16*)p; p += nS * 2;          //  64 MiB

    cast_setup<<<dim3(32, 32, 18), dim3(32, 8), 0, stream>>>(
        data, Wq, Wk, Wv, dataH, WqT, WkT, WvH);

    mega<M_MT><<<dim3(128), dim3(512), 0, stream>>>(
        dataH, WvH, WqT, WkT, MTp, Qp, VTa, S16, P16, out);

    mega<M_PROJ><<<dim3(1024), dim3(512), 0, stream>>>(
        dataH, WvH, WqT, WkT, MTp, Qp, VTa, S16, P16, out);

    mega<M_QK><<<dim3(320), dim3(512), 0, stream>>>(
        dataH, WvH, WqT, WkT, MTp, Qp, VTa, S16, P16, out);

    softmax16<<<dim3(T, B * H), dim3(256), 0, stream>>>(S16, P16);

    mega<M_PV><<<dim3(256), dim3(512), 0, stream>>>(
        dataH, WvH, WqT, WkT, MTp, Qp, VTa, S16, P16, out);
}